// Round 4
// baseline (296.425 us; speedup 1.0000x reference)
//
#include <hip/hip_runtime.h>
#include <hip/hip_fp16.h>

// OrthoLinear: out[32,8192] = x @ (dequant int4 W)^T + alpha * x @ CSR^T
// Strategy:
//  - prep kernel: zero d_out; split x into x_hi/x_lo bf16 (double-bf16 ~ f32 accurate),
//    build xT bf16 [8192][32] for sparse gathers.
//  - fused kernel: dense int4 GEMM via mfma_f32_16x16x32_bf16 (W streamed straight
//    from global, dequant via v_cvt_pk_bf16_f32; no LDS staging since zero reuse),
//    K split 8 ways for occupancy, atomicAdd f32 epilogue. Then sparse CSR phase:
//    wave-per-row, lane-per-nnz, 32-deep register accumulator, LDS reduce (stride 33).
// R1 fix: ortho_vals arrives as float32 (harness canonicalizes f16 -> f32; the
//    dtype contract lists only bf16/f32/int). Reading it as __half produced
//    +/-6e4-magnitude junk -> absmax 2.1e4.
// R2/R3: resubmit unchanged (bench never ran: GPUAcquisitionTimeout).

#define IN_F 8192
#define OUT_F 8192
#define NROW 32
#define KSPLIT 8
#define KSEG (IN_F / KSPLIT)   // 1024
#define CHUNKS (KSEG / 32)     // 32

typedef __attribute__((ext_vector_type(8))) short short8v;
typedef __attribute__((ext_vector_type(4))) float f32x4;

union Frag {
  int4 v;
  unsigned int u[4];
  short8v s;
};

__device__ __forceinline__ unsigned int cvt_pk_bf16(float lo, float hi) {
  unsigned int r;
  asm("v_cvt_pk_bf16_f32 %0, %1, %2" : "=v"(r) : "v"(lo), "v"(hi));
  return r;
}

__device__ __forceinline__ unsigned short f2bf(float f) {
  unsigned int u = __float_as_uint(f);
  u += 0x7FFFu + ((u >> 16) & 1u);  // round-to-nearest-even
  return (unsigned short)(u >> 16);
}

__global__ __launch_bounds__(256) void prep_kernel(
    const float* __restrict__ x, unsigned short* __restrict__ x_hi,
    unsigned short* __restrict__ x_lo, unsigned short* __restrict__ xTb,
    float* __restrict__ out) {
  int t = blockIdx.x * 256 + threadIdx.x;
  if (t < NROW * IN_F) {
    out[t] = 0.0f;  // d_out is poisoned 0xAA before every call
    float v = x[t];
    unsigned short h = f2bf(v);
    float hf = __uint_as_float((unsigned int)h << 16);
    unsigned short l = f2bf(v - hf);
    x_hi[t] = h;
    x_lo[t] = l;
    int n = t >> 13;          // row (0..31)
    int k = t & (IN_F - 1);   // col
    xTb[k * NROW + n] = h;
  }
}

__global__ __launch_bounds__(256) void fused_kernel(
    const int* __restrict__ packed, const float* __restrict__ scales,
    const float* __restrict__ vals, const int* __restrict__ cols,
    const int* __restrict__ rptr, const float* __restrict__ alphap,
    const unsigned short* __restrict__ x_hi,
    const unsigned short* __restrict__ x_lo,
    const unsigned short* __restrict__ xTb, float* __restrict__ out) {
  __shared__ float red[4][64 * 33];  // per-wave reduce scratch, stride 33 = conflict-free
  int tid = threadIdx.x;
  int lane = tid & 63;
  int w = tid >> 6;
  int og = blockIdx.x >> 3;   // 0..127  (64 output rows each)
  int g = blockIdx.x & 7;     // K-segment 0..7
  int lo16 = lane & 15;
  int lhi = lane >> 4;

  // ---------------- dense int4 GEMM phase ----------------
  // wave w owns o-tile [og*64 + w*16, +16), K range [g*1024, +1024)
  int o = og * 64 + w * 16 + lo16;
  int kbeg = g * KSEG;
  // B-frag (W^T): lane holds W[o][kc + 8*lhi + 0..7] -> 4 consecutive packed int32
  const int4* wp = (const int4*)(packed + (size_t)o * (IN_F / 2) + (kbeg >> 1)) + lhi;
  // A-frag (x): lane holds x[m = lo16 (+16)][kc + 8*lhi + 0..7]
  const unsigned short* xh = x_hi + lo16 * IN_F + kbeg + 8 * lhi;
  const unsigned short* xl = x_lo + lo16 * IN_F + kbeg + 8 * lhi;

  f32x4 acc0 = {0.f, 0.f, 0.f, 0.f};
  f32x4 acc1 = {0.f, 0.f, 0.f, 0.f};

  for (int c = 0; c < CHUNKS; ++c) {
    int4 p = wp[c * 4];  // 4 int32, each low byte = 2 nibbles = w[2j], w[2j+1]
    Frag b;
    b.u[0] = cvt_pk_bf16((float)(p.x & 15) - 8.0f, (float)(p.x >> 4) - 8.0f);
    b.u[1] = cvt_pk_bf16((float)(p.y & 15) - 8.0f, (float)(p.y >> 4) - 8.0f);
    b.u[2] = cvt_pk_bf16((float)(p.z & 15) - 8.0f, (float)(p.z >> 4) - 8.0f);
    b.u[3] = cvt_pk_bf16((float)(p.w & 15) - 8.0f, (float)(p.w >> 4) - 8.0f);
    Frag a0h, a0l, a1h, a1l;
    a0h.v = *(const int4*)(xh + c * 32);
    a0l.v = *(const int4*)(xl + c * 32);
    a1h.v = *(const int4*)(xh + 16 * IN_F + c * 32);
    a1l.v = *(const int4*)(xl + 16 * IN_F + c * 32);
    // hi and lo accumulate into the SAME acc: (x_hi + x_lo) * W
    acc0 = __builtin_amdgcn_mfma_f32_16x16x32_bf16(a0h.s, b.s, acc0, 0, 0, 0);
    acc0 = __builtin_amdgcn_mfma_f32_16x16x32_bf16(a0l.s, b.s, acc0, 0, 0, 0);
    acc1 = __builtin_amdgcn_mfma_f32_16x16x32_bf16(a1h.s, b.s, acc1, 0, 0, 0);
    acc1 = __builtin_amdgcn_mfma_f32_16x16x32_bf16(a1l.s, b.s, acc1, 0, 0, 0);
  }
  // C layout: col = lane&15 (= o), row = (lane>>4)*4 + r (= x-row within m-tile)
  float sc = scales[o];
#pragma unroll
  for (int r = 0; r < 4; ++r) {
    int m = lhi * 4 + r;
    atomicAdd(&out[(size_t)m * OUT_F + o], sc * acc0[r]);
    atomicAdd(&out[(size_t)(m + 16) * OUT_F + o], sc * acc1[r]);
  }

  // ---------------- sparse CSR phase ----------------
  // block covers rows [og*64 + g*8, +8); wave w owns 2 of them
  float alpha = alphap[0];
  float* R = red[w];
#pragma unroll 1
  for (int rr = 0; rr < 2; ++rr) {
    int ro = og * 64 + g * 8 + w * 2 + rr;
    int js = rptr[ro], je = rptr[ro + 1];
    float acc[32];
#pragma unroll
    for (int i = 0; i < 32; ++i) acc[i] = 0.f;
    for (int j = js + lane; j < je; j += 64) {
      float v = vals[j];
      int col = cols[j];
      const int4* xp = (const int4*)(xTb + col * NROW);  // 64B row of xT
      int4 q0 = xp[0], q1 = xp[1], q2 = xp[2], q3 = xp[3];
#define UNP(dw, base)                                                      \
  {                                                                        \
    unsigned int ud = (unsigned int)(dw);                                  \
    acc[base] = fmaf(v, __uint_as_float(ud << 16), acc[base]);             \
    acc[base + 1] = fmaf(v, __uint_as_float(ud & 0xFFFF0000u), acc[base + 1]); \
  }
      UNP(q0.x, 0) UNP(q0.y, 2) UNP(q0.z, 4) UNP(q0.w, 6)
      UNP(q1.x, 8) UNP(q1.y, 10) UNP(q1.z, 12) UNP(q1.w, 14)
      UNP(q2.x, 16) UNP(q2.y, 18) UNP(q2.z, 20) UNP(q2.w, 22)
      UNP(q3.x, 24) UNP(q3.y, 26) UNP(q3.z, 28) UNP(q3.w, 30)
#undef UNP
    }
    // transpose-reduce via LDS: lane l writes acc[0..31] at stride-33 rows
#pragma unroll
    for (int i = 0; i < 32; ++i) R[lane * 33 + i] = acc[i];
    __syncthreads();
    int cidx = lane & 31;
    int h = lane >> 5;
    float sum = 0.f;
#pragma unroll
    for (int r = 0; r < 32; ++r) sum += R[(h * 32 + r) * 33 + cidx];
    sum += __shfl_xor(sum, 32, 64);
    if (lane < 32) atomicAdd(&out[(size_t)lane * OUT_F + ro], alpha * sum);
    __syncthreads();
  }
}

extern "C" void kernel_launch(void* const* d_in, const int* in_sizes, int n_in,
                              void* d_out, int out_size, void* d_ws, size_t ws_size,
                              hipStream_t stream) {
  const float* x = (const float*)d_in[0];
  const int* packed = (const int*)d_in[1];
  const float* scales = (const float*)d_in[2];
  const float* vals = (const float*)d_in[3];
  const int* cols = (const int*)d_in[4];
  const int* rptr = (const int*)d_in[5];
  const float* alphap = (const float*)d_in[6];
  float* out = (float*)d_out;

  unsigned short* x_hi = (unsigned short*)d_ws;                  // 512 KB
  unsigned short* x_lo = x_hi + NROW * IN_F;                     // 512 KB
  unsigned short* xTb = x_lo + NROW * IN_F;                      // 512 KB

  prep_kernel<<<(NROW * IN_F + 255) / 256, 256, 0, stream>>>(x, x_hi, x_lo, xTb, out);
  fused_kernel<<<(OUT_F / 64) * KSPLIT, 256, 0, stream>>>(
      packed, scales, vals, cols, rptr, alphap, x_hi, x_lo, xTb, out);
}